// Round 8
// baseline (61.365 us; speedup 1.0000x reference)
//
#include <hip/hip_runtime.h>
#include <hip/hip_bf16.h>

typedef __bf16 v8bf __attribute__((ext_vector_type(8)));
typedef float f32x16 __attribute__((ext_vector_type(16)));
typedef unsigned int uint;
typedef unsigned short ushort;

__device__ inline f32x16 zero16() {
  f32x16 z;
#pragma unroll
  for (int i = 0; i < 16; i++) z[i] = 0.f;
  return z;
}

__device__ inline uint pack_bf16(float a, float b) {
  union { __bf16 h[2]; uint u; } c;
  c.h[0] = (__bf16)a;
  c.h[1] = (__bf16)b;
  return c.u;
}

// ---------------------------------------------------------------------------
// Kernel 0: Wf = [Wq|Wk|Wv]^T as bf16 MFMA B-FRAGMENTS, fragment-major:
// frag_linear = ((t*2 + wn)*3 + nf)*4 + ks   (t = k>>6, 384 frags x 1KB)
// byte = frag_linear*1024 + lane*16, lane = (k>>3 & 1)*32 + (n_within_32)
// Each wave-step B-fragment load in proj is then ONE coalesced 1KB dwordx4.
// 48 blocks = 3 mats x 16 k-chunks; tile 64k x 64h.
// ---------------------------------------------------------------------------
__global__ void prep_wt(const float* __restrict__ Wq, const float* __restrict__ Wk,
                        const float* __restrict__ Wv, char* __restrict__ Wf) {
  __shared__ __bf16 tile[64][74];
  const int mat = blockIdx.x >> 4;
  const int kt = blockIdx.x & 15;  // 64-wide k chunk index (t)
  const float* src = (mat == 0) ? Wq : (mat == 1) ? Wk : Wv;
  const int th = threadIdx.x;  // 256 threads
  {
    const int r = th >> 2;          // k-local 0..63
    const int ch = (th & 3) * 16;   // h chunk
    const float4* s4 = (const float4*)(src + (size_t)(kt * 64 + r) * 64 + ch);
#pragma unroll
    for (int j = 0; j < 4; j++) {
      float4 f = s4[j];
      tile[r][ch + 4 * j + 0] = (__bf16)f.x;
      tile[r][ch + 4 * j + 1] = (__bf16)f.y;
      tile[r][ch + 4 * j + 2] = (__bf16)f.z;
      tile[r][ch + 4 * j + 3] = (__bf16)f.w;
    }
  }
  __syncthreads();
  const int h = th >> 2;          // output col n-part, 0..63
  const int cc = (th & 3) * 16;   // k-local chunk of 16
  union { __bf16 o[16]; uint4 u[2]; } pk;
#pragma unroll
  for (int j = 0; j < 16; j++) pk.o[j] = tile[cc + j][h];
  const int n = mat * 64 + h;           // 0..191
  const int wn = (n >= 96) ? 1 : 0;
  const int within = n - wn * 96;
  const int nf = within >> 5;
  const int c = within & 31;
  const int ks = cc >> 4;
  const size_t fb = (size_t)((((kt * 2 + wn) * 3 + nf) * 4) + ks) * 1024;
  *(uint4*)(Wf + fb + c * 16) = pk.u[0];          // hi=0 half (k 0..7 of 16)
  *(uint4*)(Wf + fb + (32 + c) * 16) = pk.u[1];   // hi=1 half (k 8..15)
}

// ---------------------------------------------------------------------------
// Kernel 1: KQV[32768][192] = x * W. 512 blocks x 256 threads, 2 blocks/CU.
// Block tile 64x192; wave tile 32x96; BK=64.
// A: coalesced float4 -> regs (4-deep pipe) -> bf16 -> swizzled LDS dbuf
//    (16 KB total LDS).
// W: NO LDS — 12 fragment loads per wave-step, straight from L2 (fragment-
//    major Wf layout, 1KB coalesced each) into registers.
// Barrier per step = lgkmcnt(0) + s_barrier ONLY: no vmem drain anywhere in
// the main loop; A(HBM) and W(L2) loads fly across barriers, waited per-wave
// at their consume points (compiler-counted vmcnt).
// ---------------------------------------------------------------------------
__launch_bounds__(256, 2)
__global__ void proj_kernel(const float* __restrict__ x, const char* __restrict__ Wf,
                            __bf16* __restrict__ KQV) {
  __shared__ char Alds[2][8192];  // [64 rows][128 B] bf16, XOR-swizzled

  const int tid = threadIdx.x;
  const int lane = tid & 63;
  const int wave = tid >> 6;  // 0..3
  const int wm = wave >> 1;
  const int wn = wave & 1;
  const int row0 = blockIdx.x * 64;

  // A staging: thread owns row sr, 16 contiguous floats at col sc*16
  const int sr = tid >> 2;
  const int sc = tid & 3;
  const float4* xp = (const float4*)(x + (size_t)(row0 + sr) * 1024 + sc * 16);
  // W fragment base for this wave/lane
  const char* wbase = Wf + (size_t)wn * 12288 + lane * 16;

  f32x16 acc[3];
#pragma unroll
  for (int i = 0; i < 3; i++) acc[i] = zero16();

  float4 s0[4], s1[4], s2[4], s3[4];  // A register pipe (period-4)
  v8bf wf[12];                        // this step's W fragments (nf*4+ks)

#define LOADA(rr, T)                                                              \
  {                                                                               \
    _Pragma("unroll") for (int j = 0; j < 4; j++) rr[j] = xp[(T) * 16 + j];       \
  }

#define LOADW(T)                                                                  \
  {                                                                               \
    _Pragma("unroll") for (int f = 0; f < 12; f++)                                \
      wf[f] = *(const v8bf*)(wbase + (size_t)(T) * 24576 + f * 1024);             \
  }

#define CVTWRITE(rr, P)                                                           \
  {                                                                               \
    union { __bf16 h[16]; uint4 u[2]; } cv;                                       \
    _Pragma("unroll") for (int j = 0; j < 4; j++) {                               \
      cv.h[4 * j + 0] = (__bf16)rr[j].x;                                          \
      cv.h[4 * j + 1] = (__bf16)rr[j].y;                                          \
      cv.h[4 * j + 2] = (__bf16)rr[j].z;                                          \
      cv.h[4 * j + 3] = (__bf16)rr[j].w;                                          \
    }                                                                             \
    *(uint4*)(Alds[P] + sr * 128 + ((sc * 32) ^ ((sr & 7) << 4))) = cv.u[0];      \
    *(uint4*)(Alds[P] + sr * 128 + ((sc * 32 + 16) ^ ((sr & 7) << 4))) = cv.u[1]; \
  }

#define MMA(P)                                                                    \
  {                                                                               \
    _Pragma("unroll") for (int ks = 0; ks < 4; ks++) {                            \
      int arow = wm * 32 + (lane & 31);                                           \
      int kb = ks * 32 + ((lane >> 5) << 4);                                      \
      v8bf av = *(const v8bf*)(Alds[P] + arow * 128 + (kb ^ ((arow & 7) << 4)));  \
      _Pragma("unroll") for (int nf = 0; nf < 3; nf++)                            \
        acc[nf] = __builtin_amdgcn_mfma_f32_32x32x16_bf16(av, wf[nf * 4 + ks],    \
                                                          acc[nf], 0, 0, 0);      \
    }                                                                             \
  }

  // barrier: LDS-only fence. No vmem drain — global loads cross freely.
#define LBAR                                                                      \
  do {                                                                            \
    asm volatile("s_waitcnt lgkmcnt(0)" ::: "memory");                            \
    __builtin_amdgcn_s_barrier();                                                 \
  } while (0)

  // STEP T: LOADW first, LOADA second (in-order vmcnt: waiting on W at the
  // MFMA leaves the newer A-loads in flight). CVT consumes A(T+1) regs
  // (one full step of HBM cover); MMA consumes wf (CVT phase covers L2).
#define STEP(T, SN2, SN1)                                                         \
  LOADW(T);                                                                       \
  LOADA(SN2, (T) + 2);                                                            \
  CVTWRITE(SN1, ((T) + 1) & 1);                                                   \
  MMA((T) & 1);                                                                   \
  LBAR;
#define STEPL(T, SN1) /* no LOADA (tail) */                                       \
  LOADW(T);                                                                       \
  CVTWRITE(SN1, ((T) + 1) & 1);                                                   \
  MMA((T) & 1);                                                                   \
  LBAR;

  // prologue
  LOADA(s0, 0);
  LOADA(s1, 1);
  CVTWRITE(s0, 0);
  LBAR;

  STEP(0, s2, s1)
  STEP(1, s3, s2)
  STEP(2, s0, s3)
  STEP(3, s1, s0)
  STEP(4, s2, s1)
  STEP(5, s3, s2)
  STEP(6, s0, s3)
  STEP(7, s1, s0)
  STEP(8, s2, s1)
  STEP(9, s3, s2)
  STEP(10, s0, s3)
  STEP(11, s1, s0)
  STEP(12, s2, s1)
  STEP(13, s3, s2)
  STEPL(14, s3)  // consumes s[(14+1)&3] = s3
  // step 15: last compute, no staging, no barrier
  LOADW(15);
  MMA(1);

  // epilogue: write bf16 KQV
#pragma unroll
  for (int nf = 0; nf < 3; nf++) {
#pragma unroll
    for (int r = 0; r < 16; r++) {
      int row = row0 + wm * 32 + (r & 3) + ((r >> 2) << 3) + ((lane >> 5) << 2);
      int col = wn * 96 + nf * 32 + (lane & 31);
      KQV[(size_t)row * 192 + col] = (__bf16)acc[nf][r];
    }
  }
#undef STEP
#undef STEPL
#undef LBAR
#undef LOADA
#undef LOADW
#undef CVTWRITE
#undef MMA
}

// ---------------------------------------------------------------------------
// Kernel 2: causal attention per batch. 256 blocks (= 128 batches x 2 halves)
// x 256 threads (4 waves). Wave owns 32 q-rows. Swapped QK^T -> lane-local
// softmax. (unchanged from R5 — validated)
// ---------------------------------------------------------------------------
__launch_bounds__(256, 1)
__global__ void attn_kernel(const __bf16* __restrict__ KQV, float* __restrict__ out) {
  __shared__ uint4 lds4[81920 / 16];  // K:[256][64] 32KB | Vt:[64][256] 32KB | Q:[128][64] 16KB
  char* Klds = (char*)lds4;
  char* Vlds = (char*)lds4 + 32768;
  char* Qlds = (char*)lds4 + 65536;

  const int tid = threadIdx.x;
  const int lane = tid & 63;
  const int wave = tid >> 6;  // 0..3
  const int b = blockIdx.x >> 1;
  const int half = blockIdx.x & 1;
  const int bt0 = half * 128;
  const size_t base = (size_t)b * 256 * 192;

  {
    int s = tid;
    const uint4* src = (const uint4*)(KQV + base + (size_t)s * 192 + 64);
#pragma unroll
    for (int i = 0; i < 8; i++) {
      uint4 v = src[i];
      int byte = s * 128 + ((i * 16) ^ ((s & 7) << 4));
      *(uint4*)(Klds + byte) = v;
    }
  }
  {
    int s = tid;
    const uint4* src = (const uint4*)(KQV + base + (size_t)s * 192 + 128);
#pragma unroll
    for (int i = 0; i < 8; i++) {
      uint4 v = src[i];
      const ushort* e = (const ushort*)&v;
#pragma unroll
      for (int j = 0; j < 8; j++) {
        int h = i * 8 + j;
        int byte = h * 512 + ((s * 2) ^ ((h & 7) << 4));
        *(ushort*)(Vlds + byte) = e[j];
      }
    }
  }
#pragma unroll
  for (int i = 0; i < 4; i++) {
    int c = tid + i * 256;
    int r = c >> 3, cc = c & 7;
    uint4 v = *(const uint4*)(KQV + base + (size_t)(bt0 + r) * 192 + cc * 8);
    int byte = r * 128 + ((cc * 16) ^ ((r & 7) << 4));
    *(uint4*)(Qlds + byte) = v;
  }
  __syncthreads();

  const int t0 = bt0 + wave * 32;
  const int tg = t0 + (lane & 31);
  const int nf = (t0 >> 5) + 1;

  f32x16 sacc[8];
#pragma unroll
  for (int sf = 0; sf < 8; sf++) {
    f32x16 sv = zero16();
    if (sf < nf) {
#pragma unroll
      for (int ks = 0; ks < 4; ks++) {
        int kbyte = ks * 32 + ((lane >> 5) << 4);
        int krow = sf * 32 + (lane & 31);
        v8bf a = *(const v8bf*)(Klds + krow * 128 + (kbyte ^ ((krow & 7) << 4)));
        int qrow = wave * 32 + (lane & 31);
        v8bf bq = *(const v8bf*)(Qlds + qrow * 128 + (kbyte ^ ((qrow & 7) << 4)));
        sv = __builtin_amdgcn_mfma_f32_32x32x16_bf16(a, bq, sv, 0, 0, 0);
      }
    }
    sacc[sf] = sv;
  }

  float m = -1e30f;
#pragma unroll
  for (int sf = 0; sf < 8; sf++) {
    if (sf < nf) {
#pragma unroll
      for (int r = 0; r < 16; r++) {
        int sg = sf * 32 + (r & 3) + ((r >> 2) << 3) + ((lane >> 5) << 2);
        float v = sacc[sf][r] * 0.125f;
        v = (sg > tg) ? -1e30f : v;
        sacc[sf][r] = v;
        m = fmaxf(m, v);
      }
    }
  }
  m = fmaxf(m, __shfl_xor(m, 32, 64));
  float l = 0.f;
#pragma unroll
  for (int sf = 0; sf < 8; sf++) {
    if (sf < nf) {
#pragma unroll
      for (int r = 0; r < 16; r++) {
        float p = __expf(sacc[sf][r] - m);
        sacc[sf][r] = p;
        l += p;
      }
    }
  }
  l += __shfl_xor(l, 32, 64);
  float inv = 1.0f / l;

  f32x16 oacc[2];
  oacc[0] = zero16();
  oacc[1] = zero16();
  const bool hiLane = (lane >= 32);
#pragma unroll
  for (int sf = 0; sf < 8; sf++) {
    if (sf < nf) {
      uint w[8], ow[8];
#pragma unroll
      for (int q = 0; q < 4; q++) {
        w[2 * q]     = pack_bf16(sacc[sf][4 * q] * inv,     sacc[sf][4 * q + 1] * inv);
        w[2 * q + 1] = pack_bf16(sacc[sf][4 * q + 2] * inv, sacc[sf][4 * q + 3] * inv);
      }
#pragma unroll
      for (int i = 0; i < 8; i++) ow[i] = (uint)__shfl_xor((int)w[i], 32, 64);
#pragma unroll
      for (int ks = 0; ks < 2; ks++) {
        int bse = 4 * ks;
        union { uint u[4]; v8bf v; } A;
        A.u[0] = hiLane ? ow[bse + 2] : w[bse + 0];
        A.u[1] = hiLane ? ow[bse + 3] : w[bse + 1];
        A.u[2] = hiLane ? w[bse + 2] : ow[bse + 0];
        A.u[3] = hiLane ? w[bse + 3] : ow[bse + 1];
        int sbyte0 = (sf * 32 + ks * 16) * 2 + ((lane >> 5) << 4);
#pragma unroll
        for (int hf = 0; hf < 2; hf++) {
          int vrow = hf * 32 + (lane & 31);
          v8bf bv = *(const v8bf*)(Vlds + vrow * 512 + (sbyte0 ^ ((vrow & 7) << 4)));
          oacc[hf] = __builtin_amdgcn_mfma_f32_32x32x16_bf16(A.v, bv, oacc[hf], 0, 0, 0);
        }
      }
    }
  }

#pragma unroll
  for (int hf = 0; hf < 2; hf++) {
#pragma unroll
    for (int r = 0; r < 16; r++) {
      int t = t0 + (r & 3) + ((r >> 2) << 3) + ((lane >> 5) << 2);
      int h = hf * 32 + (lane & 31);
      out[((size_t)b * 256 + t) * 64 + h] = oacc[hf][r];
    }
  }
}

// ---------------------------------------------------------------------------
extern "C" void kernel_launch(void* const* d_in, const int* in_sizes, int n_in,
                              void* d_out, int out_size, void* d_ws, size_t ws_size,
                              hipStream_t stream) {
  const float* x  = (const float*)d_in[0];
  const float* Wk = (const float*)d_in[1];
  const float* Wq = (const float*)d_in[2];
  const float* Wv = (const float*)d_in[3];
  float* out = (float*)d_out;

  // workspace: KQV bf16 [32768][192] (12.58 MB), then fragment-major Wf (384 KB)
  __bf16* KQV = (__bf16*)d_ws;
  char* Wf = (char*)d_ws + (size_t)32768 * 192 * 2;

  prep_wt<<<48, 256, 0, stream>>>(Wq, Wk, Wv, Wf);
  proj_kernel<<<512, 256, 0, stream>>>(x, Wf, KQV);
  attn_kernel<<<256, 256, 0, stream>>>(KQV, out);
}